// Round 8
// baseline (79.200 us; speedup 1.0000x reference)
//
#include <hip/hip_runtime.h>

#define P_SZ 1152
#define DP 8
#define DS 16
#define NTHR 512
#define PT 9             // p's per thread per b: p = r*128 + pq
#define NW 8             // waves per block

// R7 champion structure with two VALU-issue cuts:
// 1) uh1 (second b's u_hat, 36 floats/thread) lives in LDS as float2
//    [r*2+h][t] (73.7 KB, 8B lane stride = free 2-way banking). Persistent
//    registers drop 72->~52 floats -> whole state fits the arch VGPR file,
//    eliminating the v_accvgpr shuttle (~250 VALU/thread) that VGPR_Count=60
//    + zero-scratch revealed in R7. Each thread reads only its own entries
//    -> no barrier needed for uh1s.
// 2) fp32 divides (16/thread, ~10 insts each slow-path) -> v_rcp_f32 /
//    v_sqrt_f32 single-inst forms (~1 ulp, absmax budget 10x headroom).
// Unchanged: quad layout (4 lanes/p), vacc trick (b_logits = vacc.uh
// recomputed in softmax pass), sched_barrier in build (spill guard),
// cap (512,4)=128, 2 blocks/CU.
__global__ __launch_bounds__(NTHR, 4)
void caps_routing10(const float* __restrict__ x, const float* __restrict__ W,
                    float* __restrict__ out) {
    __shared__ float2 uh1s[2 * PT * NTHR];   // 73.7 KB  [r*2+h][t]
    __shared__ float red[2][NW][2][17];      // 2.2 KB   [buf][wave][b][j,16=esum]

    const int t    = threadIdx.x;
    const int lane = t & 63;
    const int jq   = t & 3;
    const int pq   = t >> 2;
    const int w    = t >> 6;
    const int bid  = blockIdx.x;
    const int s    = bid & 31;            // same-s blocks share one XCD L2
    const int b0   = (bid >> 5) << 1;

    float uh0[PT][4];

    const float* xb0 = x + (size_t)b0 * (P_SZ * DP);
    const float* xb1 = xb0 + P_SZ * DP;

    // ---- build u_hat: per quad, 4 jq lanes cover one p's 512 B of W ----
    #pragma unroll
    for (int r = 0; r < PT; ++r) {
        const int p = (r << 7) + pq;
        const float* wp = W + (size_t)(s * P_SZ + p) * (DS * DP) + jq * DP;
        const float4 xa0 = *(const float4*)(xb0 + p * DP);
        const float4 xa1 = *(const float4*)(xb0 + p * DP + 4);
        const float4 xc0 = *(const float4*)(xb1 + p * DP);
        const float4 xc1 = *(const float4*)(xb1 + p * DP + 4);
        float u1[4];
        #pragma unroll
        for (int jj = 0; jj < 4; ++jj) {   // j = jq + 4*jj
            const float4 w0 = *(const float4*)(wp + jj * 32);
            const float4 w1 = *(const float4*)(wp + jj * 32 + 4);
            uh0[r][jj] = w0.x*xa0.x + w0.y*xa0.y + w0.z*xa0.z + w0.w*xa0.w
                       + w1.x*xa1.x + w1.y*xa1.y + w1.z*xa1.z + w1.w*xa1.w;
            u1[jj]     = w0.x*xc0.x + w0.y*xc0.y + w0.z*xc0.z + w0.w*xc0.w
                       + w1.x*xc1.x + w1.y*xc1.y + w1.z*xc1.z + w1.w*xc1.w;
        }
        uh1s[(2*r+0)*NTHR + t] = make_float2(u1[0], u1[1]);
        uh1s[(2*r+1)*NTHR + t] = make_float2(u1[2], u1[3]);
        __builtin_amdgcn_sched_barrier(0);   // cap in-flight loads at 1 iter
    }

    // ---------------- iteration 0: c = 1/P ----------------
    float sv0[4], sv1[4];
    #pragma unroll
    for (int jj = 0; jj < 4; ++jj) { sv0[jj] = 0.f; sv1[jj] = 0.f; }
    #pragma unroll
    for (int r = 0; r < PT; ++r) {
        const float2 A = uh1s[(2*r+0)*NTHR + t];
        const float2 B = uh1s[(2*r+1)*NTHR + t];
        sv0[0] += uh0[r][0]; sv0[1] += uh0[r][1];
        sv0[2] += uh0[r][2]; sv0[3] += uh0[r][3];
        sv1[0] += A.x; sv1[1] += A.y; sv1[2] += B.x; sv1[3] += B.y;
    }
    #pragma unroll
    for (int off = 4; off < 64; off <<= 1) {
        #pragma unroll
        for (int jj = 0; jj < 4; ++jj) {
            sv0[jj] += __shfl_xor(sv0[jj], off);
            sv1[jj] += __shfl_xor(sv1[jj], off);
        }
    }
    if (lane < 4) {
        #pragma unroll
        for (int jj = 0; jj < 4; ++jj) {
            red[0][w][0][jq + 4*jj] = sv0[jj];
            red[0][w][1][jq + 4*jj] = sv1[jj];
        }
    }
    __syncthreads();
    #pragma unroll
    for (int jj = 0; jj < 4; ++jj) { sv0[jj] = 0.f; sv1[jj] = 0.f; }
    #pragma unroll
    for (int ww = 0; ww < NW; ++ww) {
        #pragma unroll
        for (int jj = 0; jj < 4; ++jj) {
            sv0[jj] += red[0][ww][0][jq + 4*jj];   // same-address broadcast reads
            sv1[jj] += red[0][ww][1][jq + 4*jj];
        }
    }
    #pragma unroll
    for (int jj = 0; jj < 4; ++jj) { sv0[jj] *= (1.f / P_SZ); sv1[jj] *= (1.f / P_SZ); }

    float sq0 = sv0[0]*sv0[0] + sv0[1]*sv0[1] + sv0[2]*sv0[2] + sv0[3]*sv0[3];
    float sq1 = sv1[0]*sv1[0] + sv1[1]*sv1[1] + sv1[2]*sv1[2] + sv1[3]*sv1[3];
    sq0 += __shfl_xor(sq0, 1); sq0 += __shfl_xor(sq0, 2);
    sq1 += __shfl_xor(sq1, 1); sq1 += __shfl_xor(sq1, 2);
    float f0 = sq0 * __builtin_amdgcn_rcpf(
        (1.f + sq0) * (__builtin_amdgcn_sqrtf(sq0) + 1e-7f));
    float f1 = sq1 * __builtin_amdgcn_rcpf(
        (1.f + sq1) * (__builtin_amdgcn_sqrtf(sq1) + 1e-7f));
    // vacc = accumulated v across iterations (replaces b_logits entirely)
    float va0[4], va1[4];
    #pragma unroll
    for (int jj = 0; jj < 4; ++jj) { va0[jj] = f0 * sv0[jj]; va1[jj] = f1 * sv1[jj]; }

    // ---------------- iterations 1, 2 ----------------
    #pragma unroll
    for (int it = 1; it < 3; ++it) {
        float es0 = 0.f, es1 = 0.f;
        #pragma unroll
        for (int jj = 0; jj < 4; ++jj) { sv0[jj] = 0.f; sv1[jj] = 0.f; }
        // fused: logit (= vacc . uh, quad-reduced) -> exp -> softmax num+denom
        #pragma unroll
        for (int r = 0; r < PT; ++r) {
            const float2 A = uh1s[(2*r+0)*NTHR + t];
            const float2 B = uh1s[(2*r+1)*NTHR + t];
            float d0 = va0[0]*uh0[r][0] + va0[1]*uh0[r][1]
                     + va0[2]*uh0[r][2] + va0[3]*uh0[r][3];
            float d1 = va1[0]*A.x + va1[1]*A.y + va1[2]*B.x + va1[3]*B.y;
            d0 += __shfl_xor(d0, 1); d0 += __shfl_xor(d0, 2);
            d1 += __shfl_xor(d1, 1); d1 += __shfl_xor(d1, 2);
            const float e0 = __expf(d0);
            const float e1 = __expf(d1);
            es0 += e0; es1 += e1;
            sv0[0] += e0 * uh0[r][0]; sv0[1] += e0 * uh0[r][1];
            sv0[2] += e0 * uh0[r][2]; sv0[3] += e0 * uh0[r][3];
            sv1[0] += e1 * A.x; sv1[1] += e1 * A.y;
            sv1[2] += e1 * B.x; sv1[3] += e1 * B.y;
        }
        #pragma unroll
        for (int off = 4; off < 64; off <<= 1) {   // joint 10-value wave reduce
            es0 += __shfl_xor(es0, off);
            es1 += __shfl_xor(es1, off);
            #pragma unroll
            for (int jj = 0; jj < 4; ++jj) {
                sv0[jj] += __shfl_xor(sv0[jj], off);
                sv1[jj] += __shfl_xor(sv1[jj], off);
            }
        }
        const int buf = it & 1;
        if (lane < 4) {
            #pragma unroll
            for (int jj = 0; jj < 4; ++jj) {
                red[buf][w][0][jq + 4*jj] = sv0[jj];
                red[buf][w][1][jq + 4*jj] = sv1[jj];
            }
            if (lane == 0) { red[buf][w][0][16] = es0; red[buf][w][1][16] = es1; }
        }
        __syncthreads();
        es0 = 0.f; es1 = 0.f;
        #pragma unroll
        for (int jj = 0; jj < 4; ++jj) { sv0[jj] = 0.f; sv1[jj] = 0.f; }
        #pragma unroll
        for (int ww = 0; ww < NW; ++ww) {
            es0 += red[buf][ww][0][16];
            es1 += red[buf][ww][1][16];
            #pragma unroll
            for (int jj = 0; jj < 4; ++jj) {
                sv0[jj] += red[buf][ww][0][jq + 4*jj];
                sv1[jj] += red[buf][ww][1][jq + 4*jj];
            }
        }
        const float r0 = __builtin_amdgcn_rcpf(es0);
        const float r1 = __builtin_amdgcn_rcpf(es1);
        #pragma unroll
        for (int jj = 0; jj < 4; ++jj) { sv0[jj] *= r0; sv1[jj] *= r1; }

        sq0 = sv0[0]*sv0[0] + sv0[1]*sv0[1] + sv0[2]*sv0[2] + sv0[3]*sv0[3];
        sq1 = sv1[0]*sv1[0] + sv1[1]*sv1[1] + sv1[2]*sv1[2] + sv1[3]*sv1[3];
        sq0 += __shfl_xor(sq0, 1); sq0 += __shfl_xor(sq0, 2);
        sq1 += __shfl_xor(sq1, 1); sq1 += __shfl_xor(sq1, 2);
        f0 = sq0 * __builtin_amdgcn_rcpf(
            (1.f + sq0) * (__builtin_amdgcn_sqrtf(sq0) + 1e-7f));
        f1 = sq1 * __builtin_amdgcn_rcpf(
            (1.f + sq1) * (__builtin_amdgcn_sqrtf(sq1) + 1e-7f));

        if (it == 2) {
            if (t < 4) {
                #pragma unroll
                for (int jj = 0; jj < 4; ++jj)
                    out[(size_t)(b0 * 32 + s) * DS + jq + 4*jj] = f0 * sv0[jj];
            } else if (t < 8) {
                #pragma unroll
                for (int jj = 0; jj < 4; ++jj)
                    out[(size_t)((b0 + 1) * 32 + s) * DS + jq + 4*jj] = f1 * sv1[jj];
            }
        } else {
            #pragma unroll
            for (int jj = 0; jj < 4; ++jj) {
                va0[jj] += f0 * sv0[jj];
                va1[jj] += f1 * sv1[jj];
            }
        }
    }
}

extern "C" void kernel_launch(void* const* d_in, const int* in_sizes, int n_in,
                              void* d_out, int out_size, void* d_ws, size_t ws_size,
                              hipStream_t stream) {
    const float* x = (const float*)d_in[0];   // (128, 1152, 8) fp32
    const float* W = (const float*)d_in[1];   // (32, 1152, 16, 8) fp32
    float* out = (float*)d_out;               // (128, 32, 16) fp32
    caps_routing10<<<dim3(32 * 64), dim3(NTHR), 0, stream>>>(x, W, out);
}

// Round 9
// 77.283 us; speedup vs baseline: 1.0248x; 1.0248x over previous
//
#include <hip/hip_runtime.h>

#define P_SZ 1152
#define DP 8
#define DS 16
#define NTHR 512
#define PT 9             // p's per thread per b: p = r*128 + pq
#define NW 8             // waves per block

// R7 champion structure (quad layout, uh in registers, vacc trick,
// sched_barrier spill-guard in build, cap (512,4)) + three VALU cuts:
// 1) Two-stage cross-wave reduce: old code had EVERY thread sum 8 wave-
//    partials from LDS (80 ds_read + 80 v_add per thread per iter x3).
//    Now: butterfly -> red[w][b][jx]; sync; 34 threads produce fin[2][17];
//    sync; everyone reads 10 broadcast floats. Barriers make red/fin reuse
//    safe without double-buffering.
// 2) v_rcp_f32 / v_sqrt_f32 intrinsics for the 16 divides (R8 proved
//    bit-neutral on absmax).
// 3) Build addresses: incremented base pointers, 8 W loads share one base
//    via <=1600B immediate offsets (kills per-r 64-bit address recompute).
__global__ __launch_bounds__(NTHR, 4)
void caps_routing11(const float* __restrict__ x, const float* __restrict__ W,
                    float* __restrict__ out) {
    __shared__ float red[NW][2][17];   // per-wave partials [w][b][j=0..15,16=esum]
    __shared__ float fin[2][17];       // block totals

    const int t    = threadIdx.x;
    const int lane = t & 63;
    const int jq   = t & 3;
    const int pq   = t >> 2;
    const int w    = t >> 6;
    const int bid  = blockIdx.x;
    const int s    = bid & 31;            // same-s blocks share one XCD L2
    const int b0   = (bid >> 5) << 1;

    float uh0[PT][4], uh1[PT][4];

    // ---- build u_hat: per quad, 4 jq lanes cover one p's 512 B of W ----
    {
        const float* wp = W + ((size_t)s * P_SZ + pq) * (DS * DP) + jq * DP;
        const float* xa = x + (size_t)b0 * (P_SZ * DP) + pq * DP;
        const float* xc = xa + P_SZ * DP;
        #pragma unroll
        for (int r = 0; r < PT; ++r) {
            const float4 xa0 = *(const float4*)(xa);
            const float4 xa1 = *(const float4*)(xa + 4);
            const float4 xc0 = *(const float4*)(xc);
            const float4 xc1 = *(const float4*)(xc + 4);
            #pragma unroll
            for (int jj = 0; jj < 4; ++jj) {   // j = jq + 4*jj
                const float4 w0 = *(const float4*)(wp + jj * 32);
                const float4 w1 = *(const float4*)(wp + jj * 32 + 4);
                uh0[r][jj] = w0.x*xa0.x + w0.y*xa0.y + w0.z*xa0.z + w0.w*xa0.w
                           + w1.x*xa1.x + w1.y*xa1.y + w1.z*xa1.z + w1.w*xa1.w;
                uh1[r][jj] = w0.x*xc0.x + w0.y*xc0.y + w0.z*xc0.z + w0.w*xc0.w
                           + w1.x*xc1.x + w1.y*xc1.y + w1.z*xc1.z + w1.w*xc1.w;
            }
            wp += 128 * (DS * DP);            // advance 128 p's
            xa += 128 * DP;
            xc += 128 * DP;
            __builtin_amdgcn_sched_barrier(0);   // cap in-flight loads at 1 iter
        }
    }

    // ---------------- iteration 0: c = 1/P ----------------
    float sv0[4], sv1[4];
    #pragma unroll
    for (int jj = 0; jj < 4; ++jj) {
        float a = 0.f, c = 0.f;
        #pragma unroll
        for (int r = 0; r < PT; ++r) { a += uh0[r][jj]; c += uh1[r][jj]; }
        sv0[jj] = a; sv1[jj] = c;
    }
    #pragma unroll
    for (int off = 4; off < 64; off <<= 1) {
        #pragma unroll
        for (int jj = 0; jj < 4; ++jj) {
            sv0[jj] += __shfl_xor(sv0[jj], off);
            sv1[jj] += __shfl_xor(sv1[jj], off);
        }
    }
    if (lane < 4) {
        #pragma unroll
        for (int jj = 0; jj < 4; ++jj) {
            red[w][0][jq + 4*jj] = sv0[jj];
            red[w][1][jq + 4*jj] = sv1[jj];
        }
    }
    __syncthreads();
    if (t < 34) {                         // 34 threads: [b][jx], jx=16 unused here
        const int b  = t / 17, jx = t % 17;
        float a = 0.f;
        #pragma unroll
        for (int ww = 0; ww < NW; ++ww) a += red[ww][b][jx];
        fin[b][jx] = a;
    }
    __syncthreads();
    #pragma unroll
    for (int jj = 0; jj < 4; ++jj) {
        sv0[jj] = fin[0][jq + 4*jj] * (1.f / P_SZ);
        sv1[jj] = fin[1][jq + 4*jj] * (1.f / P_SZ);
    }

    float sq0 = sv0[0]*sv0[0] + sv0[1]*sv0[1] + sv0[2]*sv0[2] + sv0[3]*sv0[3];
    float sq1 = sv1[0]*sv1[0] + sv1[1]*sv1[1] + sv1[2]*sv1[2] + sv1[3]*sv1[3];
    sq0 += __shfl_xor(sq0, 1); sq0 += __shfl_xor(sq0, 2);
    sq1 += __shfl_xor(sq1, 1); sq1 += __shfl_xor(sq1, 2);
    float f0 = sq0 * __builtin_amdgcn_rcpf(
        (1.f + sq0) * (__builtin_amdgcn_sqrtf(sq0) + 1e-7f));
    float f1 = sq1 * __builtin_amdgcn_rcpf(
        (1.f + sq1) * (__builtin_amdgcn_sqrtf(sq1) + 1e-7f));
    // vacc = accumulated v across iterations (replaces b_logits entirely)
    float va0[4], va1[4];
    #pragma unroll
    for (int jj = 0; jj < 4; ++jj) { va0[jj] = f0 * sv0[jj]; va1[jj] = f1 * sv1[jj]; }

    // ---------------- iterations 1, 2 ----------------
    #pragma unroll
    for (int it = 1; it < 3; ++it) {
        float es0 = 0.f, es1 = 0.f;
        #pragma unroll
        for (int jj = 0; jj < 4; ++jj) { sv0[jj] = 0.f; sv1[jj] = 0.f; }
        // fused: logit (= vacc . uh, quad-reduced) -> exp -> softmax num+denom
        #pragma unroll
        for (int r = 0; r < PT; ++r) {
            float d0 = va0[0]*uh0[r][0] + va0[1]*uh0[r][1]
                     + va0[2]*uh0[r][2] + va0[3]*uh0[r][3];
            float d1 = va1[0]*uh1[r][0] + va1[1]*uh1[r][1]
                     + va1[2]*uh1[r][2] + va1[3]*uh1[r][3];
            d0 += __shfl_xor(d0, 1); d0 += __shfl_xor(d0, 2);
            d1 += __shfl_xor(d1, 1); d1 += __shfl_xor(d1, 2);
            const float e0 = __expf(d0);
            const float e1 = __expf(d1);
            es0 += e0; es1 += e1;
            #pragma unroll
            for (int jj = 0; jj < 4; ++jj) {
                sv0[jj] += e0 * uh0[r][jj];
                sv1[jj] += e1 * uh1[r][jj];
            }
        }
        #pragma unroll
        for (int off = 4; off < 64; off <<= 1) {   // joint 10-value wave reduce
            es0 += __shfl_xor(es0, off);
            es1 += __shfl_xor(es1, off);
            #pragma unroll
            for (int jj = 0; jj < 4; ++jj) {
                sv0[jj] += __shfl_xor(sv0[jj], off);
                sv1[jj] += __shfl_xor(sv1[jj], off);
            }
        }
        if (lane < 4) {
            #pragma unroll
            for (int jj = 0; jj < 4; ++jj) {
                red[w][0][jq + 4*jj] = sv0[jj];
                red[w][1][jq + 4*jj] = sv1[jj];
            }
            if (lane == 0) { red[w][0][16] = es0; red[w][1][16] = es1; }
        }
        __syncthreads();
        if (t < 34) {
            const int b  = t / 17, jx = t % 17;
            float a = 0.f;
            #pragma unroll
            for (int ww = 0; ww < NW; ++ww) a += red[ww][b][jx];
            fin[b][jx] = a;
        }
        __syncthreads();
        es0 = fin[0][16]; es1 = fin[1][16];
        const float r0 = __builtin_amdgcn_rcpf(es0);
        const float r1 = __builtin_amdgcn_rcpf(es1);
        #pragma unroll
        for (int jj = 0; jj < 4; ++jj) {
            sv0[jj] = fin[0][jq + 4*jj] * r0;
            sv1[jj] = fin[1][jq + 4*jj] * r1;
        }

        sq0 = sv0[0]*sv0[0] + sv0[1]*sv0[1] + sv0[2]*sv0[2] + sv0[3]*sv0[3];
        sq1 = sv1[0]*sv1[0] + sv1[1]*sv1[1] + sv1[2]*sv1[2] + sv1[3]*sv1[3];
        sq0 += __shfl_xor(sq0, 1); sq0 += __shfl_xor(sq0, 2);
        sq1 += __shfl_xor(sq1, 1); sq1 += __shfl_xor(sq1, 2);
        f0 = sq0 * __builtin_amdgcn_rcpf(
            (1.f + sq0) * (__builtin_amdgcn_sqrtf(sq0) + 1e-7f));
        f1 = sq1 * __builtin_amdgcn_rcpf(
            (1.f + sq1) * (__builtin_amdgcn_sqrtf(sq1) + 1e-7f));

        if (it == 2) {
            if (t < 4) {
                #pragma unroll
                for (int jj = 0; jj < 4; ++jj)
                    out[(size_t)(b0 * 32 + s) * DS + jq + 4*jj] = f0 * sv0[jj];
            } else if (t < 8) {
                #pragma unroll
                for (int jj = 0; jj < 4; ++jj)
                    out[(size_t)((b0 + 1) * 32 + s) * DS + jq + 4*jj] = f1 * sv1[jj];
            }
        } else {
            #pragma unroll
            for (int jj = 0; jj < 4; ++jj) {
                va0[jj] += f0 * sv0[jj];
                va1[jj] += f1 * sv1[jj];
            }
        }
    }
}

extern "C" void kernel_launch(void* const* d_in, const int* in_sizes, int n_in,
                              void* d_out, int out_size, void* d_ws, size_t ws_size,
                              hipStream_t stream) {
    const float* x = (const float*)d_in[0];   // (128, 1152, 8) fp32
    const float* W = (const float*)d_in[1];   // (32, 1152, 16, 8) fp32
    float* out = (float*)d_out;               // (128, 32, 16) fp32
    caps_routing11<<<dim3(32 * 64), dim3(NTHR), 0, stream>>>(x, W, out);
}